// Round 8
// baseline (3901.597 us; speedup 1.0000x reference)
//
#include <hip/hip_runtime.h>

// ---------------------------------------------------------------------------
// Model: x:(256,1,96) -> 24-layer biLSTM (scan over batch axis: N=96 rows are
// independent chains, T=256 steps) -> slice n in [48,96) -> 24-layer biLSTM
// (N=48) -> z=h2+x1 -> fc1(1536->1000,relu) -> fc2(1000->48) -> FP32 out.
//
// Round-8: round-7 counters showed the scan is dependency-LATENCY-bound
// (wall ~430 cyc/step vs ~160 issue): one dependent chain per wave leaves
// the trans/DPP/readlane latency exposed. Fix: run BOTH direction scans in
// ONE wave (independent chains -> mutual latency hiding). Wave 0 executes
// fwd step t and bwd step 255-t each iteration with separate whF/whB,
// hsF/hsB, cF/cB state. Same 2-barrier layer structure as round 7 (no
// flags/rings). Phase X (4 waves, dual-dir gate compute) unchanged.
// ---------------------------------------------------------------------------

template <int SEL>
__device__ __forceinline__ float quad_bcast(float v) {
  return __int_as_float(__builtin_amdgcn_update_dpp(
      0, __float_as_int(v), SEL * 0x55, 0xF, 0xF, true));
}

// x1g/h2g: (256,1536) row-major, k = n2*32 + d*16 + j  (n2 = n-48)
__global__ __launch_bounds__(256) void lstm_chain(
    const float* __restrict__ x, const float* __restrict__ W_ih0_1,
    const float* __restrict__ W_ih_1, const float* __restrict__ W_hh_1,
    const float* __restrict__ b_ih_1, const float* __restrict__ b_hh_1,
    const float* __restrict__ W_ih_2, const float* __restrict__ W_hh_2,
    const float* __restrict__ b_ih_2, const float* __restrict__ b_hh_2,
    float* __restrict__ x1g, float* __restrict__ h2g) {
  __shared__ float xgF[256 * 64];  // fwd gates; h_F lives in cols 32..47
  __shared__ float xgB[256 * 64];  // bwd gates; h_B lives in cols 48..63

  const int tid = threadIdx.x;
  const int lane = tid & 63;
  const int w = tid >> 6;
  const int n = blockIdx.x;
  const int nlay = (n < 48) ? 24 : 48;

  for (int L = 0; L < nlay; ++L) {
    const bool s2 = (L >= 24);
    const int l = s2 ? (L - 24) : L;
    const float* bih = s2 ? b_ih_2 : b_ih_1;
    const float* bhh = s2 ? b_hh_2 : b_hh_1;
    const float biasF = bih[l * 128 + lane] + bhh[l * 128 + lane];
    const float biasB = bih[l * 128 + 64 + lane] + bhh[l * 128 + 64 + lane];

    // scan-wave Whh loads hoisted above phase X so the (possibly cold) global
    // loads overlap the gate FMAs instead of serializing after the barrier.
    const int jj = lane >> 2, g = lane & 3;
    const int r = g * 16 + jj;
    float whF[16], whB[16];
    if (w == 0) {
      const float* Whh =
          s2 ? (W_hh_2 + (size_t)l * 2048) : (W_hh_1 + (size_t)l * 2048);
#pragma unroll
      for (int k = 0; k < 16; ++k) {
        whF[k] = Whh[(size_t)r * 16 + k];
        whB[k] = Whh[((size_t)64 + r) * 16 + k];
      }
    }

    // ---- phase X: gate pre-activations for BOTH directions ----
    if (L == 0) {
      xgF[tid * 64 + 32] = x[(size_t)tid * 96 + n];  // stage x (in_sz=1)
      const float w0F = W_ih0_1[lane];
      const float w0B = W_ih0_1[64 + lane];
      __syncthreads();
      for (int ti = 0; ti < 64; ++ti) {
        const int t = w * 64 + ti;
        const float xs = xgF[t * 64 + 32];  // read precedes write (same wave)
        xgF[t * 64 + lane] = fmaf(w0F, xs, biasF);
        xgB[t * 64 + lane] = fmaf(w0B, xs, biasB);
      }
    } else {
      const float* Wih = s2 ? (W_ih_2 + (size_t)l * 4096)
                            : (W_ih_1 + (size_t)(l - 1) * 4096);
      float wf[32], wb[32];
      {
        const float4* wpF =
            reinterpret_cast<const float4*>(Wih + (size_t)lane * 32);
        const float4* wpB =
            reinterpret_cast<const float4*>(Wih + (size_t)(64 + lane) * 32);
#pragma unroll
        for (int q = 0; q < 8; ++q) {
          const float4 a = wpF[q];
          wf[4 * q + 0] = a.x; wf[4 * q + 1] = a.y;
          wf[4 * q + 2] = a.z; wf[4 * q + 3] = a.w;
          const float4 b = wpB[q];
          wb[4 * q + 0] = b.x; wb[4 * q + 1] = b.y;
          wb[4 * q + 2] = b.z; wb[4 * q + 3] = b.w;
        }
      }
      for (int ti = 0; ti < 64; ++ti) {
        const int t = w * 64 + ti;
        const float4* hf4 = reinterpret_cast<const float4*>(&xgF[t * 64 + 32]);
        const float4* hb4 = reinterpret_cast<const float4*>(&xgB[t * 64 + 48]);
        float4 in[8];
#pragma unroll
        for (int q = 0; q < 4; ++q) in[q] = hf4[q];
#pragma unroll
        for (int q = 0; q < 4; ++q) in[4 + q] = hb4[q];
        float a0 = biasF, a1 = 0.f, a2 = 0.f, a3 = 0.f;
        float c0 = biasB, c1 = 0.f, c2 = 0.f, c3 = 0.f;
#pragma unroll
        for (int q = 0; q < 8; ++q) {
          const float4 v = in[q];
          a0 = fmaf(wf[4 * q + 0], v.x, a0);
          a1 = fmaf(wf[4 * q + 1], v.y, a1);
          a2 = fmaf(wf[4 * q + 2], v.z, a2);
          a3 = fmaf(wf[4 * q + 3], v.w, a3);
          c0 = fmaf(wb[4 * q + 0], v.x, c0);
          c1 = fmaf(wb[4 * q + 1], v.y, c1);
          c2 = fmaf(wb[4 * q + 2], v.z, c2);
          c3 = fmaf(wb[4 * q + 3], v.w, c3);
        }
        // reads of row t precede these writes (same wave, in-order DS)
        xgF[t * 64 + lane] = (a0 + a1) + (a2 + a3);
        xgB[t * 64 + lane] = (c0 + c1) + (c2 + c3);
      }
    }
    __syncthreads();

    // ---- dual scan: wave 0 runs fwd(t) and bwd(255-t) concurrently ----
    if (w == 0) {
      const float s_ = (g == 2) ? 2.885390082f : -1.442695041f;
      const float m_ = (g == 2) ? -2.0f : 1.0f;
      const float b_ = (g == 2) ? 1.0f : 0.0f;
      float hsF[16], hsB[16];
#pragma unroll
      for (int k = 0; k < 16; ++k) { hsF[k] = 0.f; hsB[k] = 0.f; }
      float cF = 0.f, cB = 0.f;
      int tF = 0, tB = 255;
      float curF0 = xgF[0 * 64 + r], curF1 = xgF[1 * 64 + r];
      float curB0 = xgB[255 * 64 + r], curB1 = xgB[254 * 64 + r];

// one LSTM step for chain SFX (F: xgF/+1/hcol 32+jj ; B: xgB/-1/hcol 48+jj)
#define LSTM_STEP(SFX, XG, CUR, TT, HCOL)                                 \
  {                                                                       \
    float a0 = (CUR), a1 = 0.f, a2 = 0.f, a3 = 0.f;                       \
    _Pragma("unroll") for (int k = 0; k < 16; k += 4) {                   \
      a0 = fmaf(wh##SFX[k + 0], hs##SFX[k + 0], a0);                      \
      a1 = fmaf(wh##SFX[k + 1], hs##SFX[k + 1], a1);                      \
      a2 = fmaf(wh##SFX[k + 2], hs##SFX[k + 2], a2);                      \
      a3 = fmaf(wh##SFX[k + 3], hs##SFX[k + 3], a3);                      \
    }                                                                     \
    const float gv = (a0 + a1) + (a2 + a3);                               \
    const float e = __builtin_amdgcn_exp2f(s_ * gv);                      \
    const float v = fmaf(m_, __builtin_amdgcn_rcpf(1.0f + e), b_);        \
    const float si = quad_bcast<0>(v);                                    \
    const float sf = quad_bcast<1>(v);                                    \
    const float tg = quad_bcast<2>(v);                                    \
    const float so = quad_bcast<3>(v);                                    \
    c##SFX = fmaf(sf, c##SFX, si * tg);                                   \
    const float e2 = __builtin_amdgcn_exp2f(2.885390082f * c##SFX);       \
    const float th = fmaf(-2.0f, __builtin_amdgcn_rcpf(1.0f + e2), 1.0f); \
    const float h = so * th;                                              \
    if (g == 0) XG[(TT)*64 + (HCOL)] = h;                                 \
    const int hbb = __float_as_int(h);                                    \
    _Pragma("unroll") for (int k = 0; k < 16; ++k) hs##SFX[k] =           \
        __int_as_float(__builtin_amdgcn_readlane(hbb, 4 * k));            \
  }

      for (int tt = 0; tt < 256; tt += 2) {
        const float nxF0 = xgF[((tF + 2) & 255) * 64 + r];
        const float nxB0 = xgB[((tB - 2) & 255) * 64 + r];
        LSTM_STEP(F, xgF, curF0, tF, 32 + jj)
        LSTM_STEP(B, xgB, curB0, tB, 48 + jj)
        const float nxF1 = xgF[((tF + 3) & 255) * 64 + r];
        const float nxB1 = xgB[((tB - 3) & 255) * 64 + r];
        LSTM_STEP(F, xgF, curF1, tF + 1, 32 + jj)
        LSTM_STEP(B, xgB, curB1, tB - 1, 48 + jj)
        curF0 = nxF0; curB0 = nxB0;
        curF1 = nxF1; curB1 = nxB1;
        tF += 2; tB -= 2;
      }
#undef LSTM_STEP
    }
    __syncthreads();

    // ---- write-out (block-uniform condition -> conditional sync is safe) --
    if ((L == 23 && n >= 48) || L == 47) {
      float* dst = (L == 23) ? x1g : h2g;
#pragma unroll
      for (int p = 0; p < 8; ++p) {
        const int idx = p * 256 + tid;
        const int t = idx >> 3, q = idx & 7;
        const float4 v =
            (q < 4) ? *reinterpret_cast<const float4*>(&xgF[t * 64 + 32 + q * 4])
                    : *reinterpret_cast<const float4*>(
                          &xgB[t * 64 + 48 + (q - 4) * 4]);
        *reinterpret_cast<float4*>(dst + (size_t)t * 1536 + (n - 48) * 32 +
                                   q * 4) = v;
      }
      __syncthreads();  // next layer's phase X overwrites the cols read above
    }
  }
}

// fc1: y1[b,m] = relu( sum_k (h2[b,k] + x1[b,k]) * w1[m,k] + b1[m] )
// 64x64 tiles, 256 threads, 4x4/thread; k-major LDS; register dbuf.
__global__ __launch_bounds__(256) void fc1_kernel(
    const float* __restrict__ h2,  // (256,1536)
    const float* __restrict__ x1,  // (256,1536)
    const float* __restrict__ w1, const float* __restrict__ b1,
    float* __restrict__ y1) {
  __shared__ float Zs[16][68];
  __shared__ float Ws[16][68];
  const int tid = threadIdx.x;
  const int m0 = blockIdx.x * 64;
  const int b0 = blockIdx.y * 64;
  const int rr = tid >> 2;
  const int c4 = (tid & 3) * 4;
  const int tx = tid & 15, ty = tid >> 4;

  float acc[4][4];
#pragma unroll
  for (int i = 0; i < 4; ++i)
#pragma unroll
    for (int jj = 0; jj < 4; ++jj) acc[i][jj] = 0.f;

  const bool wvalid = (m0 + rr) < 1000;
  const float* zr = h2 + (size_t)(b0 + rr) * 1536 + c4;
  const float* zr2 = x1 + (size_t)(b0 + rr) * 1536 + c4;
  const float* wr = w1 + (size_t)(m0 + rr) * 1536 + c4;

  float4 za = *reinterpret_cast<const float4*>(zr);
  float4 zb = *reinterpret_cast<const float4*>(zr2);
  float4 wv = wvalid ? *reinterpret_cast<const float4*>(wr)
                     : make_float4(0.f, 0.f, 0.f, 0.f);

  for (int k0 = 0; k0 < 1536; k0 += 16) {
    Zs[c4 + 0][rr] = za.x + zb.x;
    Zs[c4 + 1][rr] = za.y + zb.y;
    Zs[c4 + 2][rr] = za.z + zb.z;
    Zs[c4 + 3][rr] = za.w + zb.w;
    Ws[c4 + 0][rr] = wv.x;
    Ws[c4 + 1][rr] = wv.y;
    Ws[c4 + 2][rr] = wv.z;
    Ws[c4 + 3][rr] = wv.w;
    if (k0 + 16 < 1536) {
      za = *reinterpret_cast<const float4*>(zr + k0 + 16);
      zb = *reinterpret_cast<const float4*>(zr2 + k0 + 16);
      if (wvalid) wv = *reinterpret_cast<const float4*>(wr + k0 + 16);
    }
    __syncthreads();
#pragma unroll
    for (int kk = 0; kk < 16; ++kk) {
      const float4 av = *reinterpret_cast<const float4*>(&Zs[kk][ty * 4]);
      const float4 bv = *reinterpret_cast<const float4*>(&Ws[kk][tx * 4]);
      const float a_[4] = {av.x, av.y, av.z, av.w};
      const float b_[4] = {bv.x, bv.y, bv.z, bv.w};
#pragma unroll
      for (int i = 0; i < 4; ++i)
#pragma unroll
        for (int jj = 0; jj < 4; ++jj)
          acc[i][jj] = fmaf(a_[i], b_[jj], acc[i][jj]);
    }
    __syncthreads();
  }
#pragma unroll
  for (int i = 0; i < 4; ++i) {
    const int b = b0 + ty * 4 + i;
#pragma unroll
    for (int jj = 0; jj < 4; ++jj) {
      const int m = m0 + tx * 4 + jj;
      if (m < 1000) {
        const float vo = acc[i][jj] + b1[m];
        y1[(size_t)b * 1000 + m] = vo > 0.f ? vo : 0.f;
      }
    }
  }
}

// fc2: out[b,p] = sum_m y1[b,m]*w2[p,m] + b2[p], p<48; FP32 store.
__global__ __launch_bounds__(64) void fc2_kernel(
    const float* __restrict__ y1, const float* __restrict__ w2,
    const float* __restrict__ b2, float* __restrict__ out) {
  __shared__ float ys[1000];
  const int b = blockIdx.x;
  for (int k = threadIdx.x; k < 1000; k += 64) ys[k] = y1[(size_t)b * 1000 + k];
  __syncthreads();
  const int p = threadIdx.x;
  if (p < 48) {
    float a0 = b2[p], a1 = 0.f, a2 = 0.f, a3 = 0.f;
    const float* wr = w2 + (size_t)p * 1000;
    for (int k = 0; k < 1000; k += 4) {
      const float4 wv = *reinterpret_cast<const float4*>(wr + k);
      a0 = fmaf(ys[k + 0], wv.x, a0);
      a1 = fmaf(ys[k + 1], wv.y, a1);
      a2 = fmaf(ys[k + 2], wv.z, a2);
      a3 = fmaf(ys[k + 3], wv.w, a3);
    }
    out[(size_t)b * 48 + p] = (a0 + a1) + (a2 + a3);
  }
}

extern "C" void kernel_launch(void* const* d_in, const int* in_sizes, int n_in,
                              void* d_out, int out_size, void* d_ws,
                              size_t ws_size, hipStream_t stream) {
  const float* x = (const float*)d_in[0];
  const float* W_ih0_1 = (const float*)d_in[1];
  const float* W_ih_1 = (const float*)d_in[2];
  const float* W_hh_1 = (const float*)d_in[3];
  const float* b_ih_1 = (const float*)d_in[4];
  const float* b_hh_1 = (const float*)d_in[5];
  const float* W_ih_2 = (const float*)d_in[6];
  const float* W_hh_2 = (const float*)d_in[7];
  const float* b_ih_2 = (const float*)d_in[8];
  const float* b_hh_2 = (const float*)d_in[9];
  const float* fc1_w = (const float*)d_in[10];
  const float* fc1_b = (const float*)d_in[11];
  const float* fc2_w = (const float*)d_in[12];
  const float* fc2_b = (const float*)d_in[13];

  float* ws = (float*)d_ws;
  float* x1g = ws;           // 256*1536 = 393216
  float* h2g = ws + 393216;  // 393216
  float* y1 = ws + 786432;   // 256000

  lstm_chain<<<96, 256, 0, stream>>>(x, W_ih0_1, W_ih_1, W_hh_1, b_ih_1,
                                     b_hh_1, W_ih_2, W_hh_2, b_ih_2, b_hh_2,
                                     x1g, h2g);
  fc1_kernel<<<dim3(16, 4), 256, 0, stream>>>(h2g, x1g, fc1_w, fc1_b, y1);
  fc2_kernel<<<256, 64, 0, stream>>>(y1, fc2_w, fc2_b, (float*)d_out);
}

// Round 9
// 2631.879 us; speedup vs baseline: 1.4824x; 1.4824x over previous
//
#include <hip/hip_runtime.h>

// ---------------------------------------------------------------------------
// Model: x:(256,1,96) -> 24-layer biLSTM (scan over batch axis: N=96 rows are
// independent chains, T=256 steps) -> slice n in [48,96) -> 24-layer biLSTM
// (N=48) -> z=h2+x1 -> fc1(1536->1000,relu) -> fc2(1000->48) -> FP32 out.
//
// Round-9: round-7 structure (one block per chain, both dirs; wave 0 scans
// fwd, wave 1 scans bwd concurrently) with ONE fix: the scan no longer goes
// through a selected LDS pointer (w ? xgB : xgF). Selecting between two
// __shared__ arrays yields a GENERIC pointer -> flat_load/flat_store for LDS
// (slower, increments vmcnt AND lgkmcnt) -> suspected +150 cyc/step vs the
// round-5 per-layer kernel (280 vs 430 cyc/step). The scan is now duplicated
// per direction with direct array names (macro over the array identifier).
// Round-8's dual-chain-per-wave is reverted (falsified: stalls didn't
// overlap; +52% per step-pair).
// ---------------------------------------------------------------------------

template <int SEL>
__device__ __forceinline__ float quad_bcast(float v) {
  return __int_as_float(__builtin_amdgcn_update_dpp(
      0, __float_as_int(v), SEL * 0x55, 0xF, 0xF, true));
}

// x1g/h2g: (256,1536) row-major, k = n2*32 + d*16 + j  (n2 = n-48)
__global__ __launch_bounds__(256) void lstm_chain(
    const float* __restrict__ x, const float* __restrict__ W_ih0_1,
    const float* __restrict__ W_ih_1, const float* __restrict__ W_hh_1,
    const float* __restrict__ b_ih_1, const float* __restrict__ b_hh_1,
    const float* __restrict__ W_ih_2, const float* __restrict__ W_hh_2,
    const float* __restrict__ b_ih_2, const float* __restrict__ b_hh_2,
    float* __restrict__ x1g, float* __restrict__ h2g) {
  __shared__ float xgF[256 * 64];  // fwd gates; h_F lives in cols 32..47
  __shared__ float xgB[256 * 64];  // bwd gates; h_B lives in cols 48..63

  const int tid = threadIdx.x;
  const int lane = tid & 63;
  const int w = tid >> 6;
  const int n = blockIdx.x;
  const int nlay = (n < 48) ? 24 : 48;

  for (int L = 0; L < nlay; ++L) {
    const bool s2 = (L >= 24);
    const int l = s2 ? (L - 24) : L;
    const float* bih = s2 ? b_ih_2 : b_ih_1;
    const float* bhh = s2 ? b_hh_2 : b_hh_1;
    const float biasF = bih[l * 128 + lane] + bhh[l * 128 + lane];
    const float biasB = bih[l * 128 + 64 + lane] + bhh[l * 128 + 64 + lane];

    // scan-wave Whh loads hoisted above phase X (miss latency hides under
    // the gate FMAs). Wave 0 -> fwd rows (d=0), wave 1 -> bwd rows (d=1).
    const int jj = lane >> 2, g = lane & 3;
    const int r = g * 16 + jj;
    float whh[16];
    if (w < 2) {
      const float* Whh =
          s2 ? (W_hh_2 + (size_t)l * 2048) : (W_hh_1 + (size_t)l * 2048);
      const float* wp = Whh + ((size_t)w * 64 + r) * 16;
#pragma unroll
      for (int k = 0; k < 16; ++k) whh[k] = wp[k];
    }

    // ---- phase X: gate pre-activations for BOTH directions ----
    if (L == 0) {
      xgF[tid * 64 + 32] = x[(size_t)tid * 96 + n];  // stage x (in_sz=1)
      const float w0F = W_ih0_1[lane];
      const float w0B = W_ih0_1[64 + lane];
      __syncthreads();
      for (int ti = 0; ti < 64; ++ti) {
        const int t = w * 64 + ti;
        const float xs = xgF[t * 64 + 32];  // read precedes write (same wave)
        xgF[t * 64 + lane] = fmaf(w0F, xs, biasF);
        xgB[t * 64 + lane] = fmaf(w0B, xs, biasB);
      }
    } else {
      const float* Wih = s2 ? (W_ih_2 + (size_t)l * 4096)
                            : (W_ih_1 + (size_t)(l - 1) * 4096);
      float wf[32], wb[32];
      {
        const float4* wpF =
            reinterpret_cast<const float4*>(Wih + (size_t)lane * 32);
        const float4* wpB =
            reinterpret_cast<const float4*>(Wih + (size_t)(64 + lane) * 32);
#pragma unroll
        for (int q = 0; q < 8; ++q) {
          const float4 a = wpF[q];
          wf[4 * q + 0] = a.x; wf[4 * q + 1] = a.y;
          wf[4 * q + 2] = a.z; wf[4 * q + 3] = a.w;
          const float4 b = wpB[q];
          wb[4 * q + 0] = b.x; wb[4 * q + 1] = b.y;
          wb[4 * q + 2] = b.z; wb[4 * q + 3] = b.w;
        }
      }
      for (int ti = 0; ti < 64; ++ti) {
        const int t = w * 64 + ti;
        const float4* hf4 = reinterpret_cast<const float4*>(&xgF[t * 64 + 32]);
        const float4* hb4 = reinterpret_cast<const float4*>(&xgB[t * 64 + 48]);
        float4 in[8];
#pragma unroll
        for (int q = 0; q < 4; ++q) in[q] = hf4[q];
#pragma unroll
        for (int q = 0; q < 4; ++q) in[4 + q] = hb4[q];
        float a0 = biasF, a1 = 0.f, a2 = 0.f, a3 = 0.f;
        float c0 = biasB, c1 = 0.f, c2 = 0.f, c3 = 0.f;
#pragma unroll
        for (int q = 0; q < 8; ++q) {
          const float4 v = in[q];
          a0 = fmaf(wf[4 * q + 0], v.x, a0);
          a1 = fmaf(wf[4 * q + 1], v.y, a1);
          a2 = fmaf(wf[4 * q + 2], v.z, a2);
          a3 = fmaf(wf[4 * q + 3], v.w, a3);
          c0 = fmaf(wb[4 * q + 0], v.x, c0);
          c1 = fmaf(wb[4 * q + 1], v.y, c1);
          c2 = fmaf(wb[4 * q + 2], v.z, c2);
          c3 = fmaf(wb[4 * q + 3], v.w, c3);
        }
        // reads of row t precede these writes (same wave, in-order DS)
        xgF[t * 64 + lane] = (a0 + a1) + (a2 + a3);
        xgB[t * 64 + lane] = (c0 + c1) + (c2 + c3);
      }
    }
    __syncthreads();

    // ---- scans: wave 0 = fwd on xgF, wave 1 = bwd on xgB (concurrent) ----
    // Direct array names per branch: no generic-pointer select, so LDS ops
    // stay ds_read/ds_write (not flat_*).
    if (w < 2) {
      const float s_ = (g == 2) ? 2.885390082f : -1.442695041f;
      const float m_ = (g == 2) ? -2.0f : 1.0f;
      const float b_ = (g == 2) ? 1.0f : 0.0f;
      float hs[16];
#pragma unroll
      for (int k = 0; k < 16; ++k) hs[k] = 0.f;
      float c = 0.f;

#define LSTM_STEP(XG, CUR, TT, HCOL)                                      \
  {                                                                       \
    float a0 = (CUR), a1 = 0.f, a2 = 0.f, a3 = 0.f;                       \
    _Pragma("unroll") for (int k = 0; k < 16; k += 4) {                   \
      a0 = fmaf(whh[k + 0], hs[k + 0], a0);                               \
      a1 = fmaf(whh[k + 1], hs[k + 1], a1);                               \
      a2 = fmaf(whh[k + 2], hs[k + 2], a2);                               \
      a3 = fmaf(whh[k + 3], hs[k + 3], a3);                               \
    }                                                                     \
    const float gv = (a0 + a1) + (a2 + a3);                               \
    const float e = __builtin_amdgcn_exp2f(s_ * gv);                      \
    const float v = fmaf(m_, __builtin_amdgcn_rcpf(1.0f + e), b_);        \
    const float si = quad_bcast<0>(v);                                    \
    const float sf = quad_bcast<1>(v);                                    \
    const float tg = quad_bcast<2>(v);                                    \
    const float so = quad_bcast<3>(v);                                    \
    c = fmaf(sf, c, si * tg);                                             \
    const float e2 = __builtin_amdgcn_exp2f(2.885390082f * c);            \
    const float th = fmaf(-2.0f, __builtin_amdgcn_rcpf(1.0f + e2), 1.0f); \
    const float h = so * th;                                              \
    if (g == 0) XG[(TT)*64 + (HCOL)] = h;                                 \
    const int hbb = __float_as_int(h);                                    \
    _Pragma("unroll") for (int k = 0; k < 16; ++k) hs[k] =                \
        __int_as_float(__builtin_amdgcn_readlane(hbb, 4 * k));            \
  }

#define SCAN_LOOP(XG, DT, T0, HCOL)                                       \
  {                                                                       \
    int t = (T0);                                                         \
    float cur0 = XG[t * 64 + r];                                          \
    float cur1 = XG[(t + (DT)) * 64 + r];                                 \
    for (int tt = 0; tt < 256; tt += 2) {                                 \
      const float nx0 = XG[((t + 2 * (DT)) & 255) * 64 + r];              \
      LSTM_STEP(XG, cur0, t, HCOL)                                        \
      const float nx1 = XG[((t + 3 * (DT)) & 255) * 64 + r];              \
      LSTM_STEP(XG, cur1, t + (DT), HCOL)                                 \
      cur0 = nx0;                                                         \
      cur1 = nx1;                                                         \
      t += 2 * (DT);                                                      \
    }                                                                     \
  }

      if (w == 0) {
        SCAN_LOOP(xgF, 1, 0, 32 + jj)
      } else {
        SCAN_LOOP(xgB, -1, 255, 48 + jj)
      }
#undef SCAN_LOOP
#undef LSTM_STEP
    }
    __syncthreads();

    // ---- write-out (block-uniform condition -> conditional sync is safe) --
    if ((L == 23 && n >= 48) || L == 47) {
      float* dst = (L == 23) ? x1g : h2g;
#pragma unroll
      for (int p = 0; p < 8; ++p) {
        const int idx = p * 256 + tid;
        const int t = idx >> 3, q = idx & 7;
        const float4 v =
            (q < 4) ? *reinterpret_cast<const float4*>(&xgF[t * 64 + 32 + q * 4])
                    : *reinterpret_cast<const float4*>(
                          &xgB[t * 64 + 48 + (q - 4) * 4]);
        *reinterpret_cast<float4*>(dst + (size_t)t * 1536 + (n - 48) * 32 +
                                   q * 4) = v;
      }
      __syncthreads();  // next layer's phase X overwrites the cols read above
    }
  }
}

// fc1: y1[b,m] = relu( sum_k (h2[b,k] + x1[b,k]) * w1[m,k] + b1[m] )
// 64x64 tiles, 256 threads, 4x4/thread; k-major LDS; register dbuf.
__global__ __launch_bounds__(256) void fc1_kernel(
    const float* __restrict__ h2,  // (256,1536)
    const float* __restrict__ x1,  // (256,1536)
    const float* __restrict__ w1, const float* __restrict__ b1,
    float* __restrict__ y1) {
  __shared__ float Zs[16][68];
  __shared__ float Ws[16][68];
  const int tid = threadIdx.x;
  const int m0 = blockIdx.x * 64;
  const int b0 = blockIdx.y * 64;
  const int rr = tid >> 2;
  const int c4 = (tid & 3) * 4;
  const int tx = tid & 15, ty = tid >> 4;

  float acc[4][4];
#pragma unroll
  for (int i = 0; i < 4; ++i)
#pragma unroll
    for (int jj = 0; jj < 4; ++jj) acc[i][jj] = 0.f;

  const bool wvalid = (m0 + rr) < 1000;
  const float* zr = h2 + (size_t)(b0 + rr) * 1536 + c4;
  const float* zr2 = x1 + (size_t)(b0 + rr) * 1536 + c4;
  const float* wr = w1 + (size_t)(m0 + rr) * 1536 + c4;

  float4 za = *reinterpret_cast<const float4*>(zr);
  float4 zb = *reinterpret_cast<const float4*>(zr2);
  float4 wv = wvalid ? *reinterpret_cast<const float4*>(wr)
                     : make_float4(0.f, 0.f, 0.f, 0.f);

  for (int k0 = 0; k0 < 1536; k0 += 16) {
    Zs[c4 + 0][rr] = za.x + zb.x;
    Zs[c4 + 1][rr] = za.y + zb.y;
    Zs[c4 + 2][rr] = za.z + zb.z;
    Zs[c4 + 3][rr] = za.w + zb.w;
    Ws[c4 + 0][rr] = wv.x;
    Ws[c4 + 1][rr] = wv.y;
    Ws[c4 + 2][rr] = wv.z;
    Ws[c4 + 3][rr] = wv.w;
    if (k0 + 16 < 1536) {
      za = *reinterpret_cast<const float4*>(zr + k0 + 16);
      zb = *reinterpret_cast<const float4*>(zr2 + k0 + 16);
      if (wvalid) wv = *reinterpret_cast<const float4*>(wr + k0 + 16);
    }
    __syncthreads();
#pragma unroll
    for (int kk = 0; kk < 16; ++kk) {
      const float4 av = *reinterpret_cast<const float4*>(&Zs[kk][ty * 4]);
      const float4 bv = *reinterpret_cast<const float4*>(&Ws[kk][tx * 4]);
      const float a_[4] = {av.x, av.y, av.z, av.w};
      const float b_[4] = {bv.x, bv.y, bv.z, bv.w};
#pragma unroll
      for (int i = 0; i < 4; ++i)
#pragma unroll
        for (int jj = 0; jj < 4; ++jj)
          acc[i][jj] = fmaf(a_[i], b_[jj], acc[i][jj]);
    }
    __syncthreads();
  }
#pragma unroll
  for (int i = 0; i < 4; ++i) {
    const int b = b0 + ty * 4 + i;
#pragma unroll
    for (int jj = 0; jj < 4; ++jj) {
      const int m = m0 + tx * 4 + jj;
      if (m < 1000) {
        const float vo = acc[i][jj] + b1[m];
        y1[(size_t)b * 1000 + m] = vo > 0.f ? vo : 0.f;
      }
    }
  }
}

// fc2: out[b,p] = sum_m y1[b,m]*w2[p,m] + b2[p], p<48; FP32 store.
__global__ __launch_bounds__(64) void fc2_kernel(
    const float* __restrict__ y1, const float* __restrict__ w2,
    const float* __restrict__ b2, float* __restrict__ out) {
  __shared__ float ys[1000];
  const int b = blockIdx.x;
  for (int k = threadIdx.x; k < 1000; k += 64) ys[k] = y1[(size_t)b * 1000 + k];
  __syncthreads();
  const int p = threadIdx.x;
  if (p < 48) {
    float a0 = b2[p], a1 = 0.f, a2 = 0.f, a3 = 0.f;
    const float* wr = w2 + (size_t)p * 1000;
    for (int k = 0; k < 1000; k += 4) {
      const float4 wv = *reinterpret_cast<const float4*>(wr + k);
      a0 = fmaf(ys[k + 0], wv.x, a0);
      a1 = fmaf(ys[k + 1], wv.y, a1);
      a2 = fmaf(ys[k + 2], wv.z, a2);
      a3 = fmaf(ys[k + 3], wv.w, a3);
    }
    out[(size_t)b * 48 + p] = (a0 + a1) + (a2 + a3);
  }
}

extern "C" void kernel_launch(void* const* d_in, const int* in_sizes, int n_in,
                              void* d_out, int out_size, void* d_ws,
                              size_t ws_size, hipStream_t stream) {
  const float* x = (const float*)d_in[0];
  const float* W_ih0_1 = (const float*)d_in[1];
  const float* W_ih_1 = (const float*)d_in[2];
  const float* W_hh_1 = (const float*)d_in[3];
  const float* b_ih_1 = (const float*)d_in[4];
  const float* b_hh_1 = (const float*)d_in[5];
  const float* W_ih_2 = (const float*)d_in[6];
  const float* W_hh_2 = (const float*)d_in[7];
  const float* b_ih_2 = (const float*)d_in[8];
  const float* b_hh_2 = (const float*)d_in[9];
  const float* fc1_w = (const float*)d_in[10];
  const float* fc1_b = (const float*)d_in[11];
  const float* fc2_w = (const float*)d_in[12];
  const float* fc2_b = (const float*)d_in[13];

  float* ws = (float*)d_ws;
  float* x1g = ws;           // 256*1536 = 393216
  float* h2g = ws + 393216;  // 393216
  float* y1 = ws + 786432;   // 256000

  lstm_chain<<<96, 256, 0, stream>>>(x, W_ih0_1, W_ih_1, W_hh_1, b_ih_1,
                                     b_hh_1, W_ih_2, W_hh_2, b_ih_2, b_hh_2,
                                     x1g, h2g);
  fc1_kernel<<<dim3(16, 4), 256, 0, stream>>>(h2g, x1g, fc1_w, fc1_b, y1);
  fc2_kernel<<<256, 64, 0, stream>>>(y1, fc2_w, fc2_b, (float*)d_out);
}